// Round 8
// baseline (124.039 us; speedup 1.0000x reference)
//
#include <hip/hip_runtime.h>

// KDA delta-rule state update, B=H=32, K=V=256, fp32 — two-phase split.
//
// k1: kt[bh,v] = sum_k g[k]*key[k]*S[bh,k,v].  Read-only stream of state
//     (contiguous 1KiB rows per wave, in-lane accumulation), kt -> d_ws.
//     Plain loads so state ALLOCATES into the 256MiB Infinity Cache.
// k2: out[bh,k,v] = g[k]*S + beta*key[k]*(val[v]-kt[v]).  Pure map, no
//     reduction. Processed in DESCENDING address order (read the L3-hot
//     tail first) with non-temporal stores (hedge: don't evict state).

#define KD 256
#define VD 256
#define VD4 (VD / 4)   // 64 f32x4 per row

typedef float f32x4 __attribute__((ext_vector_type(4)));

// ---------------- k1: kt reduction (read-only) ----------------
__global__ __launch_bounds__(256, 4)
void kt_kernel(const float* __restrict__ state,
               const float* __restrict__ keys,
               const float* __restrict__ gates,
               float* __restrict__ kt)
{
    const int bh = blockIdx.x;                  // one block per (b,h) tile
    const f32x4* __restrict__ S4 = (const f32x4*)(state + (size_t)bh * KD * VD);
    const float* __restrict__ gk = gates + bh * KD;
    const float* __restrict__ kk = keys  + bh * KD;

    __shared__ f32x4 s_part[4][VD4];            // per-wave kt partials (4 KiB)

    const int t    = threadIdx.x;
    const int wv   = t >> 6;                    // wave 0..3
    const int lane = t & 63;

    // Wave wv reduces rows [64wv, 64wv+64): each row is a contiguous 1 KiB
    // wave read; kt accumulates fully in-lane (lane owns f32x4 column).
    f32x4 acc = (f32x4)(0.f);
    const int base = 64 * wv;
#pragma unroll 8
    for (int j = 0; j < 64; ++j) {
        const int k = base + j;
        const float w = gk[k] * kk[k];          // wave-uniform scalar
        const f32x4 s = S4[(size_t)k * VD4 + lane];
        acc.x = fmaf(w, s.x, acc.x);
        acc.y = fmaf(w, s.y, acc.y);
        acc.z = fmaf(w, s.z, acc.z);
        acc.w = fmaf(w, s.w, acc.w);
    }
    s_part[wv][lane] = acc;
    __syncthreads();

    if (t < VD4) {
        const f32x4 a0 = s_part[0][t], a1 = s_part[1][t];
        const f32x4 a2 = s_part[2][t], a3 = s_part[3][t];
        f32x4 r;
        r.x = (a0.x + a1.x) + (a2.x + a3.x);
        r.y = (a0.y + a1.y) + (a2.y + a3.y);
        r.z = (a0.z + a1.z) + (a2.z + a3.z);
        r.w = (a0.w + a1.w) + (a2.w + a3.w);
        ((f32x4*)kt)[(size_t)bh * VD4 + t] = r;
    }
}

// ---------------- k2: output map (write-heavy, descending) ----------------
#define ROWS_PER_BLOCK 16   // all 16 rows share one bh (16 | 256)

__global__ __launch_bounds__(256, 8)
void out_kernel(const float* __restrict__ state,
                const float* __restrict__ keys,
                const float* __restrict__ values,
                const float* __restrict__ gates,
                const float* __restrict__ beta,
                const float* __restrict__ kt,
                float* __restrict__ out)
{
    // Descending block -> address mapping: consume state from the L3-hot end.
    const int b = (int)gridDim.x - 1 - (int)blockIdx.x;

    const int t    = threadIdx.x;
    const int wv   = t >> 6;                    // wave 0..3
    const int lane = t & 63;

    const int row0 = b * ROWS_PER_BLOCK;        // first global row of block
    const int bh   = row0 >> 8;                 // same tile for all 16 rows
    const int k0   = (row0 & 255) + wv * 4;     // wave's first row-in-tile

    const f32x4 ktv = ((const f32x4*)kt)[(size_t)bh * VD4 + lane];
    const f32x4 vv  = ((const f32x4*)values)[(size_t)bh * VD4 + lane];
    f32x4 d;
    d.x = vv.x - ktv.x; d.y = vv.y - ktv.y;
    d.z = vv.z - ktv.z; d.w = vv.w - ktv.w;

    const float bta = beta[bh];
    const float* __restrict__ gk = gates + bh * KD;
    const float* __restrict__ kk = keys  + bh * KD;

    // 4 rows per wave: issue all 4 row-loads, then compute+NT-store.
    f32x4 s[4];
    float g[4], cb[4];
#pragma unroll
    for (int i = 0; i < 4; ++i) {
        const int k = k0 + i;
        s[i]  = ((const f32x4*)(state + ((size_t)bh * KD + k) * VD))[lane];
        g[i]  = gk[k];                          // wave-uniform
        cb[i] = bta * kk[k];
    }
#pragma unroll
    for (int i = 0; i < 4; ++i) {
        const int k = k0 + i;
        f32x4 o;
        o.x = fmaf(g[i], s[i].x, cb[i] * d.x);
        o.y = fmaf(g[i], s[i].y, cb[i] * d.y);
        o.z = fmaf(g[i], s[i].z, cb[i] * d.z);
        o.w = fmaf(g[i], s[i].w, cb[i] * d.w);
        __builtin_nontemporal_store(o, &((f32x4*)(out + ((size_t)bh * KD + k) * VD))[lane]);
    }
}

extern "C" void kernel_launch(void* const* d_in, const int* in_sizes, int n_in,
                              void* d_out, int out_size, void* d_ws, size_t ws_size,
                              hipStream_t stream) {
    const float* state  = (const float*)d_in[0];
    const float* keys   = (const float*)d_in[1];
    const float* values = (const float*)d_in[2];
    const float* gates  = (const float*)d_in[3];
    const float* beta   = (const float*)d_in[4];
    float* out = (float*)d_out;
    float* kt  = (float*)d_ws;   // 32*32*256 f32 = 1 MiB scratch

    // k1: kt reduction (one block per (b,h) tile)
    hipLaunchKernelGGL(kt_kernel, dim3(32 * 32), dim3(256), 0, stream,
                       state, keys, gates, kt);

    // k2: output map, 16 rows per block, descending order
    const int total_rows = 32 * 32 * KD;                 // 262144
    hipLaunchKernelGGL(out_kernel, dim3(total_rows / ROWS_PER_BLOCK), dim3(256),
                       0, stream,
                       state, keys, values, gates, beta, kt, out);
}

// Round 10
// 97.125 us; speedup vs baseline: 1.2771x; 1.2771x over previous
//
#include <hip/hip_runtime.h>

// KDA delta-rule state update, B=H=32, K=V=256, fp32.
// out[k,v] = g[k]*S[k,v] + cb[k]*(val[v] - kt[v]),
//   w[k] = g[k]*key[k], cb[k] = beta*key[k], kt[v] = sum_k w[k]*S[k,v].
//
// WAVE-AUTONOMOUS single pass: each wave owns ALL 256 rows x 32 floats
// (8 f32x4 cols). Lane (r8,c8) holds rows {r8+8j} x col c8: 32 f32x4 =
// 128 data VGPRs. Every load/store instr covers 8 x 128B full L2 lines
// (>=128B chunks -- the R6 overfetch lesson). kt reduction is fully
// in-wave: in-lane over 32 rows + 3 shfl_xor rounds over r8. NO barrier,
// NO LDS coupling after initial scalar staging -- the property shared by
// every kernel measured at >=6.1 TB/s (fills, R8-k1, R8-k2).

#define KD 256
#define VD 256
#define VD4 (VD / 4)   // 64 f32x4 per row

typedef float f32x4 __attribute__((ext_vector_type(4)));

__global__ __launch_bounds__(256, 2)
void kda_update_kernel(const float* __restrict__ state,
                       const float* __restrict__ keys,
                       const float* __restrict__ values,
                       const float* __restrict__ gates,
                       const float* __restrict__ beta,
                       float* __restrict__ out)
{
    const int bid  = blockIdx.x;
    const int bh   = bid >> 1;          // (b,h) tile
    const int half = bid & 1;           // V half (cols 0-127 / 128-255)
    const size_t toff = (size_t)bh * (KD * VD);
    const f32x4* __restrict__ S4 = (const f32x4*)(state + toff);
    f32x4* __restrict__ O4 = (f32x4*)(out + toff);

    __shared__ float s_g[KD];   // alpha
    __shared__ float s_w[KD];   // alpha*key
    __shared__ float s_c[KD];   // beta*key

    const int t    = threadIdx.x;
    const int wv   = t >> 6;            // wave 0..3
    const int lane = t & 63;
    const int r8   = lane >> 3;         // row residue 0..7
    const int c8   = lane & 7;          // f32x4 col within wave's 8
    const int col  = half * 32 + wv * 8 + c8;   // this lane's f32x4 column

    // ---- stage per-row scalars once (the only block-wide coupling) ----
    {
        const float g = gates[bh * KD + t];
        const float k = keys[bh * KD + t];
        s_g[t] = g;
        s_w[t] = g * k;
        s_c[t] = beta[bh] * k;
    }
    __syncthreads();

    // ---- load all 256 rows' worth of this lane's column (32 f32x4) ----
    f32x4 s[32];
#pragma unroll
    for (int j = 0; j < 32; ++j)
        s[j] = __builtin_nontemporal_load(&S4[(size_t)(r8 + 8 * j) * VD4 + col]);

    // ---- in-lane kt partial over this lane's 32 rows ----
    f32x4 p = (f32x4)(0.f);
#pragma unroll
    for (int j = 0; j < 32; ++j) {
        const float w = s_w[r8 + 8 * j];   // 8 banks, broadcast over c8: free
        p.x = fmaf(w, s[j].x, p.x);
        p.y = fmaf(w, s[j].y, p.y);
        p.z = fmaf(w, s[j].z, p.z);
        p.w = fmaf(w, s[j].w, p.w);
    }

    // ---- in-wave reduce over r8 (lane bits 3,4,5): 3 butterfly rounds ----
#pragma unroll
    for (int m = 8; m <= 32; m <<= 1) {
        p.x += __shfl_xor(p.x, m, 64);
        p.y += __shfl_xor(p.y, m, 64);
        p.z += __shfl_xor(p.z, m, 64);
        p.w += __shfl_xor(p.w, m, 64);
    }

    const f32x4 vv = ((const f32x4*)(values + (size_t)bh * VD))[col];
    f32x4 d;
    d.x = vv.x - p.x; d.y = vv.y - p.y;
    d.z = vv.z - p.z; d.w = vv.w - p.w;

    // ---- output: same full-line pattern, straight from registers ----
#pragma unroll
    for (int j = 0; j < 32; ++j) {
        const int r = r8 + 8 * j;
        const float g  = s_g[r];
        const float cb = s_c[r];
        f32x4 o;
        o.x = fmaf(g, s[j].x, cb * d.x);
        o.y = fmaf(g, s[j].y, cb * d.y);
        o.z = fmaf(g, s[j].z, cb * d.z);
        o.w = fmaf(g, s[j].w, cb * d.w);
        __builtin_nontemporal_store(o, &O4[(size_t)r * VD4 + col]);
    }
}

extern "C" void kernel_launch(void* const* d_in, const int* in_sizes, int n_in,
                              void* d_out, int out_size, void* d_ws, size_t ws_size,
                              hipStream_t stream) {
    const float* state  = (const float*)d_in[0];
    const float* keys   = (const float*)d_in[1];
    const float* values = (const float*)d_in[2];
    const float* gates  = (const float*)d_in[3];
    const float* beta   = (const float*)d_in[4];
    float* out = (float*)d_out;

    dim3 grid(32 * 32 * 2);   // (b,h) x 2 V-halves
    dim3 block(256);
    hipLaunchKernelGGL(kda_update_kernel, grid, block, 0, stream,
                       state, keys, values, gates, beta, out);
}